// Round 1
// baseline (276.710 us; speedup 1.0000x reference)
//
#include <hip/hip_runtime.h>
#include <cstdint>
#include <cstddef>

// LSTMCreature: seq_len=1, h0=c0=0 => each layer is GEMM(+bias) through 3 of
// 4 gates (f-gate multiplies c0=0, so skipped). W_hh unused (h0=0).
//
//   g_i = x @ Wih[0:256].T  + bih[0:256]  + bhh[0:256]
//   g_g = x @ Wih[512:768].T+ bih[512:768]+ bhh[512:768]
//   g_o = x @ Wih[768:1024].T+bih[768:1024]+bhh[768:1024]
//   h   = sigmoid(g_o) * tanh( sigmoid(g_i) * tanh(g_g) )
//
// Final: out = h @ fcW.T + fcb ; t=tanh(out); e=exp(|out|-max); Z=sum e;
//        w = t*e/Z; res = w / max(sum|w|, 1e-12)

#define NROWS 16384
#define HSZ   256

template<int K>
__global__ __launch_bounds__(256)
void lstm_layer_kernel(const float* __restrict__ in,    // NROWS x K
                       const float* __restrict__ W,     // (4*HSZ) x K row-major
                       const float* __restrict__ bih,   // 4*HSZ
                       const float* __restrict__ bhh,   // 4*HSZ
                       float* __restrict__ hout)        // NROWS x HSZ
{
    constexpr int BM = 64, BN = 64, KS = 32;
    constexpr int LDP = 68;  // pad: keeps 16B alignment (68%4==0), banks spread
    __shared__ float As[KS][LDP];        // k-major A tile: As[k][row]
    __shared__ float Ws[3][KS][LDP];     // k-major W tiles: Ws[g][k][col]

    const int t  = threadIdx.x;
    const int tx = t & 15;
    const int ty = t >> 4;
    const int n0 = blockIdx.x * BN;   // h-column block (0..3)
    const int m0 = blockIdx.y * BM;   // row block (0..255)

    float acc[3][4][4];
#pragma unroll
    for (int g = 0; g < 3; ++g)
#pragma unroll
        for (int r = 0; r < 4; ++r)
#pragma unroll
            for (int c = 0; c < 4; ++c) acc[g][r][c] = 0.f;

    for (int k0 = 0; k0 < K; k0 += KS) {
        __syncthreads();
        // ---- stage A tile (64 rows x 32 k), coalesced float4 along k ----
#pragma unroll
        for (int i = 0; i < 2; ++i) {
            int idx = t + i * 256;          // 0..511
            int row = idx >> 3;             // 0..63
            int kq  = idx & 7;              // 0..7 (k = 4*kq)
            const float4 v = *(const float4*)(in + (size_t)(m0 + row) * K + k0 + kq * 4);
            As[kq * 4 + 0][row] = v.x;
            As[kq * 4 + 1][row] = v.y;
            As[kq * 4 + 2][row] = v.z;
            As[kq * 4 + 3][row] = v.w;
        }
        // ---- stage W tiles for gates i, g, o ----
#pragma unroll
        for (int g = 0; g < 3; ++g) {
            const int gbase = (g == 0) ? 0 : (g == 1) ? 512 : 768;
#pragma unroll
            for (int i = 0; i < 2; ++i) {
                int idx = t + i * 256;
                int c   = idx >> 3;         // output column within tile
                int kq  = idx & 7;
                const float4 v = *(const float4*)(W + (size_t)(gbase + n0 + c) * K + k0 + kq * 4);
                Ws[g][kq * 4 + 0][c] = v.x;
                Ws[g][kq * 4 + 1][c] = v.y;
                Ws[g][kq * 4 + 2][c] = v.z;
                Ws[g][kq * 4 + 3][c] = v.w;
            }
        }
        __syncthreads();

        // ---- FMA inner loop: 48 FMAs per kk per thread ----
#pragma unroll 4
        for (int kk = 0; kk < KS; ++kk) {
            const float4 a  = *(const float4*)(&As[kk][ty * 4]);
            const float4 b0 = *(const float4*)(&Ws[0][kk][tx * 4]);
            const float4 b1 = *(const float4*)(&Ws[1][kk][tx * 4]);
            const float4 b2 = *(const float4*)(&Ws[2][kk][tx * 4]);
            const float av[4]  = {a.x, a.y, a.z, a.w};
            const float bv[3][4] = {{b0.x, b0.y, b0.z, b0.w},
                                    {b1.x, b1.y, b1.z, b1.w},
                                    {b2.x, b2.y, b2.z, b2.w}};
#pragma unroll
            for (int r = 0; r < 4; ++r)
#pragma unroll
                for (int c = 0; c < 4; ++c) {
                    acc[0][r][c] += av[r] * bv[0][c];
                    acc[1][r][c] += av[r] * bv[1][c];
                    acc[2][r][c] += av[r] * bv[2][c];
                }
        }
    }

    // ---- epilogue: biases + gates, write h ----
    const int nb = n0 + tx * 4;
    const float4 bi_i = *(const float4*)(bih + nb);
    const float4 bh_i = *(const float4*)(bhh + nb);
    const float4 bi_g = *(const float4*)(bih + 512 + nb);
    const float4 bh_g = *(const float4*)(bhh + 512 + nb);
    const float4 bi_o = *(const float4*)(bih + 768 + nb);
    const float4 bh_o = *(const float4*)(bhh + 768 + nb);
    const float bI[4] = {bi_i.x + bh_i.x, bi_i.y + bh_i.y, bi_i.z + bh_i.z, bi_i.w + bh_i.w};
    const float bG[4] = {bi_g.x + bh_g.x, bi_g.y + bh_g.y, bi_g.z + bh_g.z, bi_g.w + bh_g.w};
    const float bO[4] = {bi_o.x + bh_o.x, bi_o.y + bh_o.y, bi_o.z + bh_o.z, bi_o.w + bh_o.w};

#pragma unroll
    for (int r = 0; r < 4; ++r) {
        const int row = m0 + ty * 4 + r;
        float hv[4];
#pragma unroll
        for (int c = 0; c < 4; ++c) {
            const float gi = acc[0][r][c] + bI[c];
            const float gg = acc[1][r][c] + bG[c];
            const float go = acc[2][r][c] + bO[c];
            const float si = 1.f / (1.f + expf(-gi));
            const float so = 1.f / (1.f + expf(-go));
            const float c2 = si * tanhf(gg);
            hv[c] = so * tanhf(c2);
        }
        float4 o4 = {hv[0], hv[1], hv[2], hv[3]};
        *(float4*)(hout + (size_t)row * HSZ + nb) = o4;
    }
}

#define FC_ROWS 16
__global__ __launch_bounds__(256)
void fc_softmax_kernel(const float* __restrict__ h,     // NROWS x 256
                       const float* __restrict__ fcW,   // 64 x 256 row-major
                       const float* __restrict__ fcb,   // 64
                       float* __restrict__ out)         // NROWS x 64
{
    // Transposed + XOR-swizzled fc_W in LDS: element (k,j) at Wt[k][j ^ ((k>>2)&31)]
    __shared__ float Wt[256][64];
    const int t = threadIdx.x;
#pragma unroll
    for (int i = 0; i < 16; ++i) {
        int idx = t + i * 256;          // 0..4095
        int j   = idx >> 6;             // 0..63 (output col)
        int kq  = idx & 63;             // k = 4*kq
        const float4 v = *(const float4*)(fcW + (size_t)j * 256 + kq * 4);
        const int sw = j ^ (kq & 31);
        Wt[4 * kq + 0][sw] = v.x;
        Wt[4 * kq + 1][sw] = v.y;
        Wt[4 * kq + 2][sw] = v.z;
        Wt[4 * kq + 3][sw] = v.w;
    }
    __syncthreads();

    const int wave = t >> 6;
    const int lane = t & 63;
    const float fb = fcb[lane];

#pragma unroll 1
    for (int it = 0; it < FC_ROWS / 4; ++it) {
        const int b = blockIdx.x * FC_ROWS + it * 4 + wave;
        const float4* h4 = (const float4*)(h + (size_t)b * 256);
        float acc = 0.f;
#pragma unroll 8
        for (int k4 = 0; k4 < 64; ++k4) {
            const float4 hv = h4[k4];       // wave-uniform address: broadcast
            const int sw = lane ^ (k4 & 31);
            acc += hv.x * Wt[4 * k4 + 0][sw];
            acc += hv.y * Wt[4 * k4 + 1][sw];
            acc += hv.z * Wt[4 * k4 + 2][sw];
            acc += hv.w * Wt[4 * k4 + 3][sw];
        }
        const float o = acc + fb;
        const float tt = tanhf(o);
        const float a  = fabsf(o);
        float m = a;
#pragma unroll
        for (int ofs = 32; ofs > 0; ofs >>= 1) m = fmaxf(m, __shfl_xor(m, ofs, 64));
        const float e = expf(a - m);
        float Z = e;
#pragma unroll
        for (int ofs = 32; ofs > 0; ofs >>= 1) Z += __shfl_xor(Z, ofs, 64);
        const float w = tt * e / Z;
        float s = fabsf(w);
#pragma unroll
        for (int ofs = 32; ofs > 0; ofs >>= 1) s += __shfl_xor(s, ofs, 64);
        const float denom = fmaxf(s, 1e-12f);
        out[(size_t)b * 64 + lane] = w / denom;
    }
}

extern "C" void kernel_launch(void* const* d_in, const int* in_sizes, int n_in,
                              void* d_out, int out_size, void* d_ws, size_t ws_size,
                              hipStream_t stream) {
    const float* x    = (const float*)d_in[0];
    const float* Wih0 = (const float*)d_in[1];
    const float* bih0 = (const float*)d_in[3];
    const float* bhh0 = (const float*)d_in[4];
    const float* Wih1 = (const float*)d_in[5];
    const float* bih1 = (const float*)d_in[7];
    const float* bhh1 = (const float*)d_in[8];
    const float* Wih2 = (const float*)d_in[9];
    const float* bih2 = (const float*)d_in[11];
    const float* bhh2 = (const float*)d_in[12];
    const float* fcW  = (const float*)d_in[13];
    const float* fcb  = (const float*)d_in[14];

    float* hA = (float*)d_ws;                       // 16384*256 floats (16 MB)
    float* hB = hA + (size_t)NROWS * HSZ;           // another 16 MB
    float* outp = (float*)d_out;

    dim3 blk(256);
    dim3 grid(HSZ / 64, NROWS / 64);                // (4, 256)

    lstm_layer_kernel<128><<<grid, blk, 0, stream>>>(x,  Wih0, bih0, bhh0, hA);
    lstm_layer_kernel<256><<<grid, blk, 0, stream>>>(hA, Wih1, bih1, bhh1, hB);
    lstm_layer_kernel<256><<<grid, blk, 0, stream>>>(hB, Wih2, bih2, bhh2, hA);

    fc_softmax_kernel<<<dim3(NROWS / FC_ROWS), blk, 0, stream>>>(hA, fcW, fcb, outp);
}

// Round 2
// 162.512 us; speedup vs baseline: 1.7027x; 1.7027x over previous
//
#include <hip/hip_runtime.h>
#include <cstdint>
#include <cstddef>

// LSTMCreature, seq_len=1, h0=c0=0:
//   per layer: g = x @ Wih(gate rows).T + (bih+bhh); h = sig(go)*tanh(sig(gi)*tanh(gg))
//   f-gate skipped (multiplies c0=0), W_hh unused (h0=0).
// MFMA fp16 hi/lo 3-pass (Ootomo): x*w ~= xh*wh + xl*wh + xh*wl  (err ~2^-22)
//
// Pipeline:
//   split_f32(x) -> xh/xl planes      (in hB region of ws)
//   prep_w<K>    -> Wh/Wl planes + bsum (in d_out region, dead until fc)
//   lstm_mfma<K> x3 (ping-pong hA/hB half-planes)
//   fc_softmax   (reconstruct h = hi+lo, fp32 GEMV + tanh-softmax-normalize)

#define NROWS 16384
#define HSZ   256
#define NGATE 768

typedef _Float16 half8  __attribute__((ext_vector_type(8)));
typedef _Float16 half4v __attribute__((ext_vector_type(4)));
typedef float    f32x4  __attribute__((ext_vector_type(4)));

__device__ __forceinline__ void gld16(const void* g, void* l) {
    __builtin_amdgcn_global_load_lds(
        (const __attribute__((address_space(1))) void*)g,
        (__attribute__((address_space(3))) void*)l, 16, 0, 0);
}

__device__ __forceinline__ float fsig(float x)  { return 1.f / (1.f + __expf(-x)); }
__device__ __forceinline__ float ftanh(float x) { float e = __expf(2.f * x); return 1.f - 2.f / (e + 1.f); }

// ---------------- split helpers (fp32 -> hi/lo fp16 planes) ----------------

__global__ __launch_bounds__(256)
void split_f32_kernel(const float* __restrict__ in, _Float16* __restrict__ hi,
                      _Float16* __restrict__ lo, int n4) {
    int i = blockIdx.x * 256 + threadIdx.x;
    if (i >= n4) return;
    f32x4 v = ((const f32x4*)in)[i];
    half4v h, l;
#pragma unroll
    for (int j = 0; j < 4; ++j) {
        _Float16 hh = (_Float16)v[j];
        h[j] = hh;
        l[j] = (_Float16)(v[j] - (float)hh);
    }
    ((half4v*)hi)[i] = h;
    ((half4v*)lo)[i] = l;
}

// Remap gate rows {i:0,g:2,o:3} of W_ih[1024][K] into Wh/Wl[768][K]; bsum = bih+bhh.
template<int K>
__global__ __launch_bounds__(256)
void prep_w_kernel(const float* __restrict__ Wih, const float* __restrict__ bih,
                   const float* __restrict__ bhh, _Float16* __restrict__ Wh,
                   _Float16* __restrict__ Wl, float* __restrict__ bsum) {
    constexpr int K4 = K / 4;
    int i = blockIdx.x * 256 + threadIdx.x;
    if (i < NGATE * K4) {
        int row = i / K4;
        int kq  = i - row * K4;
        int r8  = row >> 8;                     // 0,1,2 -> src gates 0,2,3
        int src = ((r8 == 0) ? 0 : r8 + 1) * 256 + (row & 255);
        f32x4 v = *(const f32x4*)(Wih + (size_t)src * K + kq * 4);
        half4v h, l;
#pragma unroll
        for (int j = 0; j < 4; ++j) {
            _Float16 hh = (_Float16)v[j];
            h[j] = hh;
            l[j] = (_Float16)(v[j] - (float)hh);
        }
        *(half4v*)(Wh + (size_t)row * K + kq * 4) = h;
        *(half4v*)(Wl + (size_t)row * K + kq * 4) = l;
    }
    if (i < NGATE) {
        int r8  = i >> 8;
        int src = ((r8 == 0) ? 0 : r8 + 1) * 256 + (i & 255);
        bsum[i] = bih[src] + bhh[src];
    }
}

// ---------------- MFMA layer kernel ----------------
// BM=128 rows x BN=32 cols(per gate) x 3 gates; KS=64; 4 waves (2m x 2n).
// LDS tiles XOR-swizzled in 16B blocks: lds halfs off = r*64 + ((kb ^ (r&7))<<3).
// global_load_lds with linear LDS dest + swizzle applied to the SOURCE address.

template<int K>
__global__ __launch_bounds__(256)
void lstm_mfma_kernel(const _Float16* __restrict__ Ah, const _Float16* __restrict__ Al, // [NROWS][K]
                      const _Float16* __restrict__ Wh, const _Float16* __restrict__ Wl, // [768][K]
                      const float* __restrict__ bsum,                                   // [768]
                      _Float16* __restrict__ Oh, _Float16* __restrict__ Ol)             // [NROWS][256]
{
    __shared__ __align__(16) _Float16 sAh[128 * 64];
    __shared__ __align__(16) _Float16 sAl[128 * 64];
    __shared__ __align__(16) _Float16 sWh[96 * 64];
    __shared__ __align__(16) _Float16 sWl[96 * 64];

    const int t    = threadIdx.x;
    const int lane = t & 63;
    const int wave = t >> 6;
    const int wm   = wave >> 1;        // 0..1: M half (64 rows)
    const int wn   = wave & 1;         // 0..1: N half (16 cols)
    const int lrow = lane & 15;
    const int lkb  = lane >> 4;        // 0..3
    const int n0   = blockIdx.x * 32;  // col block within 256
    const int m0   = blockIdx.y * 128;

    f32x4 acc[3][4];
#pragma unroll
    for (int g = 0; g < 3; ++g)
#pragma unroll
        for (int fm = 0; fm < 4; ++fm) acc[g][fm] = (f32x4)0.f;

    for (int k0 = 0; k0 < K; k0 += 64) {
        __syncthreads();
        // stage A planes: 1024 x 16B chunks each
#pragma unroll
        for (int i = 0; i < 4; ++i) {
            int c   = i * 256 + t;
            int row = c >> 3;
            int kb  = (c & 7) ^ (row & 7);           // source swizzle
            size_t go = (size_t)(m0 + row) * K + k0 + kb * 8;
            gld16(Ah + go, sAh + c * 8);
            gld16(Al + go, sAl + c * 8);
        }
        // stage W planes: 768 x 16B chunks each (96 rows = 3 gates x 32 cols)
#pragma unroll
        for (int i = 0; i < 3; ++i) {
            int c    = i * 256 + t;
            int row  = c >> 3;                       // 0..95
            int kb   = (c & 7) ^ (row & 7);
            int grow = (row >> 5) * 256 + n0 + (row & 31);
            size_t go = (size_t)grow * K + k0 + kb * 8;
            gld16(Wh + go, sWh + c * 8);
            gld16(Wl + go, sWl + c * 8);
        }
        __syncthreads();  // drains vmcnt(0) before barrier -> staging complete

#pragma unroll
        for (int kk = 0; kk < 2; ++kk) {
            const int kbb = kk * 4 + lkb;
            half8 xh[4], xl[4];
#pragma unroll
            for (int fm = 0; fm < 4; ++fm) {
                int r   = wm * 64 + fm * 16 + lrow;
                int off = r * 64 + ((kbb ^ (r & 7)) << 3);
                xh[fm] = *(const half8*)(sAh + off);
                xl[fm] = *(const half8*)(sAl + off);
            }
            half8 wwh[3], wwl[3];
#pragma unroll
            for (int g = 0; g < 3; ++g) {
                int r   = g * 32 + wn * 16 + lrow;
                int off = r * 64 + ((kbb ^ (r & 7)) << 3);
                wwh[g] = *(const half8*)(sWh + off);
                wwl[g] = *(const half8*)(sWl + off);
            }
            // swapped operands: A-op = W frag, B-op = x frag -> D[n][m], lane&15 = m
#pragma unroll
            for (int g = 0; g < 3; ++g)
#pragma unroll
                for (int fm = 0; fm < 4; ++fm) {
                    acc[g][fm] = __builtin_amdgcn_mfma_f32_16x16x32_f16(wwh[g], xh[fm], acc[g][fm], 0, 0, 0);
                    acc[g][fm] = __builtin_amdgcn_mfma_f32_16x16x32_f16(wwh[g], xl[fm], acc[g][fm], 0, 0, 0);
                    acc[g][fm] = __builtin_amdgcn_mfma_f32_16x16x32_f16(wwl[g], xh[fm], acc[g][fm], 0, 0, 0);
                }
        }
    }

    // epilogue: n = n0 + wn*16 + lkb*4 + j ; m = m0 + wm*64 + fm*16 + lrow
    const int nbase = n0 + wn * 16 + lkb * 4;
    const f32x4 bI = *(const f32x4*)(bsum + nbase);
    const f32x4 bG = *(const f32x4*)(bsum + 256 + nbase);
    const f32x4 bO = *(const f32x4*)(bsum + 512 + nbase);

#pragma unroll
    for (int fm = 0; fm < 4; ++fm) {
        const int m = m0 + wm * 64 + fm * 16 + lrow;
        half4v oh, ol;
#pragma unroll
        for (int j = 0; j < 4; ++j) {
            float gi = acc[0][fm][j] + bI[j];
            float gg = acc[1][fm][j] + bG[j];
            float go = acc[2][fm][j] + bO[j];
            float c2 = fsig(gi) * ftanh(gg);
            float h  = fsig(go) * ftanh(c2);
            _Float16 hh = (_Float16)h;
            oh[j] = hh;
            ol[j] = (_Float16)(h - (float)hh);
        }
        *(half4v*)(Oh + (size_t)m * HSZ + nbase) = oh;
        *(half4v*)(Ol + (size_t)m * HSZ + nbase) = ol;
    }
}

// ---------------- FC + tanh-softmax-normalize ----------------

#define FC_ROWS 16
__global__ __launch_bounds__(256)
void fc_softmax_kernel(const _Float16* __restrict__ hhi, const _Float16* __restrict__ hlo,
                       const float* __restrict__ fcW, const float* __restrict__ fcb,
                       float* __restrict__ out) {
    __shared__ float Wt[256][64];   // transposed + XOR-swizzled fc_W
    const int t = threadIdx.x;
#pragma unroll
    for (int i = 0; i < 16; ++i) {
        int idx = t + i * 256;
        int j   = idx >> 6;
        int kq  = idx & 63;
        const float4 v = *(const float4*)(fcW + (size_t)j * 256 + kq * 4);
        const int sw = j ^ (kq & 31);
        Wt[4 * kq + 0][sw] = v.x;
        Wt[4 * kq + 1][sw] = v.y;
        Wt[4 * kq + 2][sw] = v.z;
        Wt[4 * kq + 3][sw] = v.w;
    }
    __syncthreads();

    const int wave = t >> 6;
    const int lane = t & 63;
    const float fb = fcb[lane];

#pragma unroll 1
    for (int it = 0; it < FC_ROWS / 4; ++it) {
        const int b = blockIdx.x * FC_ROWS + it * 4 + wave;
        const half4v* hh = (const half4v*)(hhi + (size_t)b * 256);
        const half4v* hl = (const half4v*)(hlo + (size_t)b * 256);
        float acc = 0.f;
#pragma unroll 8
        for (int k4 = 0; k4 < 64; ++k4) {
            half4v a = hh[k4];      // wave-uniform: broadcast
            half4v c = hl[k4];
            const int sw = lane ^ (k4 & 31);
            acc += ((float)a[0] + (float)c[0]) * Wt[4 * k4 + 0][sw];
            acc += ((float)a[1] + (float)c[1]) * Wt[4 * k4 + 1][sw];
            acc += ((float)a[2] + (float)c[2]) * Wt[4 * k4 + 2][sw];
            acc += ((float)a[3] + (float)c[3]) * Wt[4 * k4 + 3][sw];
        }
        const float o  = acc + fb;
        const float tt = tanhf(o);
        const float av = fabsf(o);
        float mx = av;
#pragma unroll
        for (int ofs = 32; ofs > 0; ofs >>= 1) mx = fmaxf(mx, __shfl_xor(mx, ofs, 64));
        const float e = expf(av - mx);
        float Z = e;
#pragma unroll
        for (int ofs = 32; ofs > 0; ofs >>= 1) Z += __shfl_xor(Z, ofs, 64);
        const float w = tt * e / Z;
        float s = fabsf(w);
#pragma unroll
        for (int ofs = 32; ofs > 0; ofs >>= 1) s += __shfl_xor(s, ofs, 64);
        out[(size_t)b * 64 + lane] = w / fmaxf(s, 1e-12f);
    }
}

// ---------------- launch ----------------

extern "C" void kernel_launch(void* const* d_in, const int* in_sizes, int n_in,
                              void* d_out, int out_size, void* d_ws, size_t ws_size,
                              hipStream_t stream) {
    const float* x    = (const float*)d_in[0];
    const float* Wih0 = (const float*)d_in[1];
    const float* bih0 = (const float*)d_in[3];
    const float* bhh0 = (const float*)d_in[4];
    const float* Wih1 = (const float*)d_in[5];
    const float* bih1 = (const float*)d_in[7];
    const float* bhh1 = (const float*)d_in[8];
    const float* Wih2 = (const float*)d_in[9];
    const float* bih2 = (const float*)d_in[11];
    const float* bhh2 = (const float*)d_in[12];
    const float* fcW  = (const float*)d_in[13];
    const float* fcb  = (const float*)d_in[14];

    char* ws = (char*)d_ws;
    _Float16* hA_hi = (_Float16*)(ws);                     // 8 MB
    _Float16* hA_lo = (_Float16*)(ws + (8u << 20));        // 8 MB
    _Float16* hB_hi = (_Float16*)(ws + (16u << 20));       // 8 MB
    _Float16* hB_lo = (_Float16*)(ws + (24u << 20));       // 8 MB
    _Float16* xh    = hB_hi;                               // 4 MB (dead before layer1 writes hB)
    _Float16* xl    = (_Float16*)(ws + (20u << 20));       // 4 MB

    // W planes + bsum staged in d_out (4 MB); fc overwrites it last.
    char* ob = (char*)d_out;
    _Float16* Whp  = (_Float16*)(ob);                      // <= 384 KB
    _Float16* Wlp  = (_Float16*)(ob + (1u << 20));
    float*    bsum = (float*)(ob + (2u << 20));            // 3 KB
    float*    outp = (float*)d_out;

    dim3 blk(256);
    dim3 lgrid(8, 128);

    split_f32_kernel<<<dim3(NROWS * 128 / 4 / 256), blk, 0, stream>>>(x, xh, xl, NROWS * 128 / 4);

    prep_w_kernel<128><<<dim3(96), blk, 0, stream>>>(Wih0, bih0, bhh0, Whp, Wlp, bsum);
    lstm_mfma_kernel<128><<<lgrid, blk, 0, stream>>>(xh, xl, Whp, Wlp, bsum, hA_hi, hA_lo);

    prep_w_kernel<256><<<dim3(192), blk, 0, stream>>>(Wih1, bih1, bhh1, Whp, Wlp, bsum);
    lstm_mfma_kernel<256><<<lgrid, blk, 0, stream>>>(hA_hi, hA_lo, Whp, Wlp, bsum, hB_hi, hB_lo);

    prep_w_kernel<256><<<dim3(192), blk, 0, stream>>>(Wih2, bih2, bhh2, Whp, Wlp, bsum);
    lstm_mfma_kernel<256><<<lgrid, blk, 0, stream>>>(hB_hi, hB_lo, Whp, Wlp, bsum, hA_hi, hA_lo);

    fc_softmax_kernel<<<dim3(NROWS / FC_ROWS), blk, 0, stream>>>(hA_hi, hA_lo, fcW, fcb, outp);
}

// Round 3
// 110.223 us; speedup vs baseline: 2.5105x; 1.4744x over previous
//
#include <hip/hip_runtime.h>
#include <cstdint>
#include <cstddef>

// LSTMCreature, seq_len=1, h0=c0=0:
//   per layer: g = x @ Wih(gate rows).T + (bih+bhh); h = sig(go)*tanh(sig(gi)*tanh(gg))
//   f-gate skipped (multiplies c0=0), W_hh unused (h0=0).
// fp16 hi/lo 3-pass MFMA (Ootomo): x*w ~= xh*wh + xl*wh + xh*wl
//
// prep_all: split x -> hi/lo planes; remap+split W0/1/2; bsum = bih+bhh (gate-remapped)
// lstm_mfma<K> x3: 2-phase dbuf KS=32, interleaved hi/lo LDS rows (128B) w/ XOR swizzle
// fc_softmax: MFMA FC (fcW converted in-LDS) + fused row softmax/normalize

#define NROWS 16384
#define HSZ   256

typedef _Float16 half8  __attribute__((ext_vector_type(8)));
typedef _Float16 half4v __attribute__((ext_vector_type(4)));
typedef float    f32x4  __attribute__((ext_vector_type(4)));

__device__ __forceinline__ void gld16(const void* g, void* l) {
    __builtin_amdgcn_global_load_lds(
        (const __attribute__((address_space(1))) void*)g,
        (__attribute__((address_space(3))) void*)l, 16, 0, 0);
}

__device__ __forceinline__ float fsig(float x)  { return 1.f / (1.f + __expf(-x)); }
__device__ __forceinline__ float ftanh(float x) { float e = __expf(2.f * x); return 1.f - 2.f / (e + 1.f); }

__device__ __forceinline__ int gate_remap(int row) {   // 768-row id -> 1024-row src (gates i,g,o)
    int g8 = row >> 8;
    int gate = (g8 == 0) ? 0 : g8 + 1;
    return gate * 256 + (row & 255);
}

// ---------------- fused prep: x split + W0/1/2 split + bsums ----------------

#define PS0 524288            /* x chunks: 16384*128/4 */
#define PS1 (PS0 + 24576)     /* W0: 768*32 */
#define PS2 (PS1 + 49152)     /* W1: 768*64 */
#define PS3 (PS2 + 49152)     /* W2 */
#define PS4 (PS3 + 2304)      /* bsums */

__global__ __launch_bounds__(256)
void prep_all_kernel(const float* __restrict__ x,
                     const float* __restrict__ W0, const float* __restrict__ b0i, const float* __restrict__ b0h,
                     const float* __restrict__ W1, const float* __restrict__ b1i, const float* __restrict__ b1h,
                     const float* __restrict__ W2, const float* __restrict__ b2i, const float* __restrict__ b2h,
                     _Float16* __restrict__ xh, _Float16* __restrict__ xl,
                     _Float16* __restrict__ W0h, _Float16* __restrict__ W0l,
                     _Float16* __restrict__ W1h, _Float16* __restrict__ W1l,
                     _Float16* __restrict__ W2h, _Float16* __restrict__ W2l,
                     float* __restrict__ bs0, float* __restrict__ bs1, float* __restrict__ bs2)
{
    const int gid = blockIdx.x * 256 + threadIdx.x;
    if (gid < PS0) {
        f32x4 v = ((const f32x4*)x)[gid];
        half4v h, l;
#pragma unroll
        for (int j = 0; j < 4; ++j) { _Float16 hh = (_Float16)v[j]; h[j] = hh; l[j] = (_Float16)(v[j] - (float)hh); }
        ((half4v*)xh)[gid] = h;
        ((half4v*)xl)[gid] = l;
    } else if (gid < PS3) {
        const float* W; _Float16 *Wh, *Wl; int j, K;
        if (gid < PS1)      { j = gid - PS0; K = 128; W = W0; Wh = W0h; Wl = W0l; }
        else if (gid < PS2) { j = gid - PS1; K = 256; W = W1; Wh = W1h; Wl = W1l; }
        else                { j = gid - PS2; K = 256; W = W2; Wh = W2h; Wl = W2l; }
        const int K4 = K >> 2;
        int row = j / K4, k4 = j - row * K4;
        int src = gate_remap(row);
        f32x4 v = *(const f32x4*)(W + (size_t)src * K + k4 * 4);
        half4v h, l;
#pragma unroll
        for (int jj = 0; jj < 4; ++jj) { _Float16 hh = (_Float16)v[jj]; h[jj] = hh; l[jj] = (_Float16)(v[jj] - (float)hh); }
        *(half4v*)(Wh + (size_t)row * K + k4 * 4) = h;
        *(half4v*)(Wl + (size_t)row * K + k4 * 4) = l;
    } else if (gid < PS4) {
        int j = gid - PS3;
        int l = (j >= 1536) ? 2 : (j >= 768 ? 1 : 0);
        int r = j - l * 768;
        int src = gate_remap(r);
        const float* bi = (l == 0) ? b0i : (l == 1) ? b1i : b2i;
        const float* bh = (l == 0) ? b0h : (l == 1) ? b1h : b2h;
        float* bs       = (l == 0) ? bs0 : (l == 1) ? bs1 : bs2;
        bs[r] = bi[src] + bh[src];
    }
}

// ---------------- MFMA layer kernel: 2-phase dbuf, KS=32 ----------------
// LDS rows = 128B = 8x16B chunks: c<4 -> hi plane kb=c; c>=4 -> lo plane kb=c-4.
// Physical chunk p holds logical chunk p ^ (row&7) (swizzle on SOURCE; linear dest).

template<int K>
__global__ __launch_bounds__(256)
void lstm_mfma_kernel(const _Float16* __restrict__ Ah, const _Float16* __restrict__ Al, // [NROWS][K]
                      const _Float16* __restrict__ Wh, const _Float16* __restrict__ Wl, // [768][K]
                      const float* __restrict__ bsum,                                   // [768]
                      _Float16* __restrict__ Oh, _Float16* __restrict__ Ol)             // [NROWS][256]
{
    __shared__ __align__(16) _Float16 sA[2][128 * 64];   // 16KB each
    __shared__ __align__(16) _Float16 sW[2][96 * 64];    // 12KB each

    const int t    = threadIdx.x;
    const int lane = t & 63;
    const int wave = t >> 6;
    const int wm   = wave >> 1;
    const int wn   = wave & 1;
    const int lrow = lane & 15;
    const int lkb  = lane >> 4;
    const int n0   = blockIdx.x * 32;
    const int m0   = blockIdx.y * 128;
    constexpr int NT = K / 32;

    f32x4 acc[3][4];
#pragma unroll
    for (int g = 0; g < 3; ++g)
#pragma unroll
        for (int fm = 0; fm < 4; ++fm) acc[g][fm] = (f32x4)0.f;

    auto stage = [&](int bi, int kt) {
        const int k0 = kt * 32;
#pragma unroll
        for (int i = 0; i < 4; ++i) {
            int idx = i * 256 + t;
            int row = idx >> 3, p = idx & 7;
            int c = p ^ (row & 7);
            const _Float16* base = (c & 4) ? Al : Ah;
            gld16(base + (size_t)(m0 + row) * K + k0 + (c & 3) * 8, &sA[bi][idx * 8]);
        }
#pragma unroll
        for (int i = 0; i < 3; ++i) {
            int idx = i * 256 + t;
            int row = idx >> 3, p = idx & 7;
            int c = p ^ (row & 7);
            int grow = (row >> 5) * 256 + n0 + (row & 31);
            const _Float16* base = (c & 4) ? Wl : Wh;
            gld16(base + (size_t)grow * K + k0 + (c & 3) * 8, &sW[bi][idx * 8]);
        }
    };

    auto compute = [&](int bi) {
        half8 xh[4], xl[4];
#pragma unroll
        for (int fm = 0; fm < 4; ++fm) {
            int r = wm * 64 + fm * 16 + lrow;
            int rb = r * 64;
            xh[fm] = *(const half8*)(&sA[bi][rb + ((lkb       ^ (r & 7)) << 3)]);
            xl[fm] = *(const half8*)(&sA[bi][rb + (((4 | lkb) ^ (r & 7)) << 3)]);
        }
        half8 wwh[3], wwl[3];
#pragma unroll
        for (int g = 0; g < 3; ++g) {
            int r = g * 32 + wn * 16 + lrow;
            int rb = r * 64;
            wwh[g] = *(const half8*)(&sW[bi][rb + ((lkb       ^ (r & 7)) << 3)]);
            wwl[g] = *(const half8*)(&sW[bi][rb + (((4 | lkb) ^ (r & 7)) << 3)]);
        }
#pragma unroll
        for (int g = 0; g < 3; ++g)
#pragma unroll
            for (int fm = 0; fm < 4; ++fm) {
                acc[g][fm] = __builtin_amdgcn_mfma_f32_16x16x32_f16(wwh[g], xh[fm], acc[g][fm], 0, 0, 0);
                acc[g][fm] = __builtin_amdgcn_mfma_f32_16x16x32_f16(wwh[g], xl[fm], acc[g][fm], 0, 0, 0);
                acc[g][fm] = __builtin_amdgcn_mfma_f32_16x16x32_f16(wwl[g], xh[fm], acc[g][fm], 0, 0, 0);
            }
    };

    stage(0, 0);
    __syncthreads();
    int cur = 0;
    for (int kt = 0; kt < NT - 1; ++kt) {
        stage(cur ^ 1, kt + 1);   // issue next tile BEFORE compute: latency hides under MFMA
        compute(cur);
        __syncthreads();          // drains vmcnt(0)+lgkmcnt(0): next tile ready
        cur ^= 1;
    }
    compute(cur);

    // epilogue: n = n0 + wn*16 + lkb*4 + j ; m = m0 + wm*64 + fm*16 + lrow
    const int nbase = n0 + wn * 16 + lkb * 4;
    const f32x4 bI = *(const f32x4*)(bsum + nbase);
    const f32x4 bG = *(const f32x4*)(bsum + 256 + nbase);
    const f32x4 bO = *(const f32x4*)(bsum + 512 + nbase);

#pragma unroll
    for (int fm = 0; fm < 4; ++fm) {
        const int m = m0 + wm * 64 + fm * 16 + lrow;
        half4v oh, ol;
#pragma unroll
        for (int j = 0; j < 4; ++j) {
            float gi = acc[0][fm][j] + bI[j];
            float gg = acc[1][fm][j] + bG[j];
            float go = acc[2][fm][j] + bO[j];
            float c2 = fsig(gi) * ftanh(gg);
            float h  = fsig(go) * ftanh(c2);
            _Float16 hh = (_Float16)h;
            oh[j] = hh;
            ol[j] = (_Float16)(h - (float)hh);
        }
        *(half4v*)(Oh + (size_t)m * HSZ + nbase) = oh;
        *(half4v*)(Ol + (size_t)m * HSZ + nbase) = ol;
    }
}

// ---------------- FC (MFMA) + fused tanh-softmax-normalize ----------------
// BM=64 rows/block, 256 blocks. fcW converted to hi/lo fp16 in LDS (swizzled).
// H staged 2-phase dbuf KS=32. D frag: col(lane&15)=n, row(lkb*4+r)=m-local.

__global__ __launch_bounds__(256)
void fc_softmax_kernel(const _Float16* __restrict__ hhi, const _Float16* __restrict__ hlo,
                       const float* __restrict__ fcW, const float* __restrict__ fcb,
                       float* __restrict__ out)
{
    __shared__ __align__(16) _Float16 sWh[64 * 256];   // 32KB, rows of 512B = 32 chunks
    __shared__ __align__(16) _Float16 sWl[64 * 256];   // 32KB
    __shared__ __align__(16) _Float16 sH[2][64 * 64];  // 8KB each

    const int t    = threadIdx.x;
    const int lane = t & 63;
    const int wave = t >> 6;
    const int ln   = lane & 15;
    const int lkb  = lane >> 4;
    const int m0   = blockIdx.x * 64;

    // convert fcW (64x256 f32) -> hi/lo fp16 LDS, 16B-chunk XOR swizzle
#pragma unroll
    for (int i = 0; i < 8; ++i) {
        int idx = i * 256 + t;            // 0..2047
        int row = idx >> 5, c = idx & 31; // chunk = 8 k
        const float* src = fcW + (size_t)row * 256 + c * 8;
        f32x4 v0 = *(const f32x4*)src;
        f32x4 v1 = *(const f32x4*)(src + 4);
        half8 h, l;
#pragma unroll
        for (int j = 0; j < 4; ++j) {
            _Float16 h0 = (_Float16)v0[j]; h[j]     = h0; l[j]     = (_Float16)(v0[j] - (float)h0);
            _Float16 h1 = (_Float16)v1[j]; h[4 + j] = h1; l[4 + j] = (_Float16)(v1[j] - (float)h1);
        }
        int off = row * 256 + ((c ^ (row & 7)) << 3);
        *(half8*)(sWh + off) = h;
        *(half8*)(sWl + off) = l;
    }

    auto stageH = [&](int bi, int kt) {
#pragma unroll
        for (int i = 0; i < 2; ++i) {
            int idx = i * 256 + t;
            int row = idx >> 3, p = idx & 7;
            int c = p ^ (row & 7);
            const _Float16* base = (c & 4) ? hlo : hhi;
            gld16(base + (size_t)(m0 + row) * 256 + kt * 32 + (c & 3) * 8, &sH[bi][idx * 8]);
        }
    };

    f32x4 acc[4];
#pragma unroll
    for (int nf = 0; nf < 4; ++nf) acc[nf] = (f32x4)0.f;

    auto computeF = [&](int bi, int kt) {
        const int r  = wave * 16 + ln;
        const int rb = r * 64;
        half8 ah = *(const half8*)(&sH[bi][rb + ((lkb       ^ (r & 7)) << 3)]);
        half8 al = *(const half8*)(&sH[bi][rb + (((4 | lkb) ^ (r & 7)) << 3)]);
#pragma unroll
        for (int nf = 0; nf < 4; ++nf) {
            int wr  = nf * 16 + ln;
            int ch  = kt * 4 + lkb;                 // logical 16B chunk in row (0..31)
            int off = wr * 256 + ((ch ^ (wr & 7)) << 3);
            half8 wwh = *(const half8*)(&sWh[off]);
            half8 wwl = *(const half8*)(&sWl[off]);
            acc[nf] = __builtin_amdgcn_mfma_f32_16x16x32_f16(ah, wwh, acc[nf], 0, 0, 0);
            acc[nf] = __builtin_amdgcn_mfma_f32_16x16x32_f16(al, wwh, acc[nf], 0, 0, 0);
            acc[nf] = __builtin_amdgcn_mfma_f32_16x16x32_f16(ah, wwl, acc[nf], 0, 0, 0);
        }
    };

    stageH(0, 0);
    __syncthreads();   // covers fcW ds_writes + first H stage
    int cur = 0;
    for (int kt = 0; kt < 7; ++kt) {
        stageH(cur ^ 1, kt + 1);
        computeF(cur, kt);
        __syncthreads();
        cur ^= 1;
    }
    computeF(cur, 7);

    // ---- epilogue: bias + tanh-softmax-normalize over n (64) per row ----
    float fb[4];
#pragma unroll
    for (int nf = 0; nf < 4; ++nf) fb[nf] = fcb[nf * 16 + ln];

    float tt[4][4], aa[4][4];
#pragma unroll
    for (int nf = 0; nf < 4; ++nf)
#pragma unroll
        for (int r = 0; r < 4; ++r) {
            float o = acc[nf][r] + fb[nf];
            tt[nf][r] = ftanh(o);
            aa[nf][r] = fabsf(o);
        }

    float mx[4];
#pragma unroll
    for (int r = 0; r < 4; ++r)
        mx[r] = fmaxf(fmaxf(aa[0][r], aa[1][r]), fmaxf(aa[2][r], aa[3][r]));
#pragma unroll
    for (int ofs = 1; ofs < 16; ofs <<= 1)
#pragma unroll
        for (int r = 0; r < 4; ++r) mx[r] = fmaxf(mx[r], __shfl_xor(mx[r], ofs, 64));

    float ee[4][4], Z[4];
#pragma unroll
    for (int r = 0; r < 4; ++r) Z[r] = 0.f;
#pragma unroll
    for (int nf = 0; nf < 4; ++nf)
#pragma unroll
        for (int r = 0; r < 4; ++r) { ee[nf][r] = __expf(aa[nf][r] - mx[r]); Z[r] += ee[nf][r]; }
#pragma unroll
    for (int ofs = 1; ofs < 16; ofs <<= 1)
#pragma unroll
        for (int r = 0; r < 4; ++r) Z[r] += __shfl_xor(Z[r], ofs, 64);

    float w[4][4], S[4];
#pragma unroll
    for (int r = 0; r < 4; ++r) S[r] = 0.f;
#pragma unroll
    for (int nf = 0; nf < 4; ++nf)
#pragma unroll
        for (int r = 0; r < 4; ++r) { w[nf][r] = tt[nf][r] * ee[nf][r] / Z[r]; S[r] += fabsf(w[nf][r]); }
#pragma unroll
    for (int ofs = 1; ofs < 16; ofs <<= 1)
#pragma unroll
        for (int r = 0; r < 4; ++r) S[r] += __shfl_xor(S[r], ofs, 64);

#pragma unroll
    for (int r = 0; r < 4; ++r) {
        const float inv = 1.f / fmaxf(S[r], 1e-12f);
        const int m = m0 + wave * 16 + lkb * 4 + r;
#pragma unroll
        for (int nf = 0; nf < 4; ++nf)
            out[(size_t)m * 64 + nf * 16 + ln] = w[nf][r] * inv;
    }
}

// ---------------- launch ----------------

extern "C" void kernel_launch(void* const* d_in, const int* in_sizes, int n_in,
                              void* d_out, int out_size, void* d_ws, size_t ws_size,
                              hipStream_t stream) {
    const float* x    = (const float*)d_in[0];
    const float* Wih0 = (const float*)d_in[1];
    const float* bih0 = (const float*)d_in[3];
    const float* bhh0 = (const float*)d_in[4];
    const float* Wih1 = (const float*)d_in[5];
    const float* bih1 = (const float*)d_in[7];
    const float* bhh1 = (const float*)d_in[8];
    const float* Wih2 = (const float*)d_in[9];
    const float* bih2 = (const float*)d_in[11];
    const float* bhh2 = (const float*)d_in[12];
    const float* fcW  = (const float*)d_in[13];
    const float* fcb  = (const float*)d_in[14];

    char* ws = (char*)d_ws;
    _Float16* hA_hi = (_Float16*)(ws);                 // 8 MB
    _Float16* hA_lo = (_Float16*)(ws + (8u  << 20));   // 8 MB
    _Float16* hB_hi = (_Float16*)(ws + (16u << 20));   // 8 MB
    _Float16* hB_lo = (_Float16*)(ws + (24u << 20));   // 8 MB
    _Float16* xh    = hB_hi;                           // 4 MB (dead after layer 1)
    _Float16* xl    = (_Float16*)(ws + (20u << 20));   // 4 MB

    // W planes + bsums live in d_out (4 MB), fully consumed before fc writes out.
    char* ob = (char*)d_out;
    _Float16* W0h = (_Float16*)(ob);
    _Float16* W0l = (_Float16*)(ob + 196608);
    _Float16* W1h = (_Float16*)(ob + 393216);
    _Float16* W1l = (_Float16*)(ob + 786432);
    _Float16* W2h = (_Float16*)(ob + 1179648);
    _Float16* W2l = (_Float16*)(ob + 1572864);
    float*    bs0 = (float*)(ob + 1966080);
    float*    bs1 = (float*)(ob + 1969152);
    float*    bs2 = (float*)(ob + 1972224);
    float*    outp = (float*)d_out;

    dim3 blk(256);
    dim3 lgrid(8, 128);

    prep_all_kernel<<<dim3(PS4 / 256), blk, 0, stream>>>(
        x, Wih0, bih0, bhh0, Wih1, bih1, bhh1, Wih2, bih2, bhh2,
        xh, xl, W0h, W0l, W1h, W1l, W2h, W2l, bs0, bs1, bs2);

    lstm_mfma_kernel<128><<<lgrid, blk, 0, stream>>>(xh, xl, W0h, W0l, bs0, hA_hi, hA_lo);
    lstm_mfma_kernel<256><<<lgrid, blk, 0, stream>>>(hA_hi, hA_lo, W1h, W1l, bs1, hB_hi, hB_lo);
    lstm_mfma_kernel<256><<<lgrid, blk, 0, stream>>>(hB_hi, hB_lo, W2h, W2l, bs2, hA_hi, hA_lo);

    fc_softmax_kernel<<<dim3(NROWS / 64), blk, 0, stream>>>(hA_hi, hA_lo, fcW, fcb, outp);
}